// Round 10
// baseline (308.151 us; speedup 1.0000x reference)
//
#include <hip/hip_runtime.h>
#include <math.h>

#define FEAT 128
#define OUTF 384
#define NRBF 20

typedef float f32x4 __attribute__((ext_vector_type(4)));
typedef _Float16 f16x4 __attribute__((ext_vector_type(4)));
typedef _Float16 f16x8 __attribute__((ext_vector_type(8)));

// Detect whether nbrs buffer is int64 (little-endian: odd int32 words are the
// high halves, all zero since indices < 50000) or genuine int32 pairs.
__device__ __forceinline__ int nbrs_is_i64(const int* nb) {
    int nz = 0;
#pragma unroll
    for (int i = 1; i < 64; i += 2) nz |= nb[i];
    return nz == 0;
}

// ---------------------------------------------------------------------------
// Convert W1 (128x128), W2 (128x384) to f16 B-fragment order and Wd (20x384)
// to f16 A-fragment order (K padded 20->32 with zeros) for mfma_f32_16x16x32:
// frag (ct, ks, lane) holds 8 f16: W[ks*32 + (lane>>4)*8 + j][ct*16 + (lane&15)]
__global__ __launch_bounds__(256) void prep_w_kernel(
    const float* __restrict__ W1, const float* __restrict__ W2,
    const float* __restrict__ Wd,
    _Float16* __restrict__ w1f, _Float16* __restrict__ w2f,
    _Float16* __restrict__ wdf)
{
    int idx = blockIdx.x * 256 + threadIdx.x;
    if (idx < 8 * 4 * 64) {                 // W1: 8 col-tiles x 4 k-steps
        int ct = idx >> 8, ks = (idx >> 6) & 3, lane = idx & 63;
        int lcol = lane & 15, lgrp = lane >> 4;
        _Float16* dst = w1f + (size_t)idx * 8;
        const float* src = W1 + (size_t)(ks * 32 + lgrp * 8) * FEAT + ct * 16 + lcol;
#pragma unroll
        for (int j = 0; j < 8; j++) dst[j] = (_Float16)src[(size_t)j * FEAT];
    } else if (idx < 8192) {                // W2: 24 col-tiles x 4 k-steps
        int i2 = idx - 2048;
        int ct = i2 >> 8, ks = (i2 >> 6) & 3, lane = i2 & 63;
        int lcol = lane & 15, lgrp = lane >> 4;
        _Float16* dst = w2f + (size_t)i2 * 8;
        const float* src = W2 + (size_t)(ks * 32 + lgrp * 8) * OUTF + ct * 16 + lcol;
#pragma unroll
        for (int j = 0; j < 8; j++) dst[j] = (_Float16)src[(size_t)j * OUTF];
    } else {                                // Wd: 24 col-tiles x 1 k-step (K=32, pad 20)
        int i3 = idx - 8192;
        if (i3 < 24 * 64) {
            int ct = i3 >> 6, lane = i3 & 63;
            int lcol = lane & 15, lgrp = lane >> 4;
            _Float16* dst = wdf + (size_t)i3 * 8;
#pragma unroll
            for (int j = 0; j < 8; j++) {
                int k = lgrp * 8 + j;
                dst[j] = (k < NRBF) ? (_Float16)Wd[(size_t)k * OUTF + ct * 16 + lcol]
                                    : (_Float16)0.f;
            }
        }
    }
}

// ---------------------------------------------------------------------------
// MFMA phi: PHI[row] = (silu(s_j[row] @ W1 + b1) @ W2 + b2) as fp16.
// 64 rows/block, 256 threads = 4 waves; wave w owns rows [w*16, w*16+16).
// mfma_f32_16x16x32_f16 layouts: A: row=lane&15, k=(lane>>4)*8+j;
// B: col=lane&15, same k; D: col=lane&15, row=(lane>>4)*4+reg.
__global__ __launch_bounds__(256) void phi_mfma_kernel(
    const float* __restrict__ s_j,
    const _Float16* __restrict__ w1f, const float* __restrict__ b1,
    const _Float16* __restrict__ w2f, const float* __restrict__ b2,
    _Float16* __restrict__ PHI, int M)
{
    __shared__ __align__(16) float s32[64][136];        // padded
    __shared__ __align__(16) _Float16 h16[4][16][144];  // wave-private H / PHI-chunk
    const int t = threadIdx.x;
    const int base = blockIdx.x * 64;

    for (int idx = t; idx < 64 * 32; idx += 256) {
        int row = idx >> 5, c4 = (idx & 31) * 4;
        float4 v = {0.f, 0.f, 0.f, 0.f};
        if (base + row < M) v = *(const float4*)(s_j + (size_t)(base + row) * FEAT + c4);
        *(float4*)&s32[row][c4] = v;
    }
    __syncthreads();

    const int w = t >> 6, lane = t & 63;
    const int lcol = lane & 15;
    const int lgrp = lane >> 4;
    const int r0 = w * 16;

    f16x8 a1[4];
#pragma unroll
    for (int ks = 0; ks < 4; ks++) {
        const float* p = &s32[r0 + lcol][ks * 32 + lgrp * 8];
        float4 u = *(const float4*)p;
        float4 v = *(const float4*)(p + 4);
        a1[ks] = (f16x8){(_Float16)u.x, (_Float16)u.y, (_Float16)u.z, (_Float16)u.w,
                         (_Float16)v.x, (_Float16)v.y, (_Float16)v.z, (_Float16)v.w};
    }

    // ---- GEMM1: H = silu(S @ W1 + b1) ----
#pragma unroll
    for (int ct = 0; ct < 8; ct++) {
        float bb = b1[ct * 16 + lcol];
        f32x4 acc = {bb, bb, bb, bb};
#pragma unroll
        for (int ks = 0; ks < 4; ks++) {
            f16x8 b = *(const f16x8*)(w1f + ((size_t)(ct * 4 + ks) * 64 + lane) * 8);
            acc = __builtin_amdgcn_mfma_f32_16x16x32_f16(a1[ks], b, acc, 0, 0, 0);
        }
#pragma unroll
        for (int r = 0; r < 4; r++) {
            float h = acc[r];
            h = h * __frcp_rn(1.f + __expf(-h));
            h16[w][lgrp * 4 + r][ct * 16 + lcol] = (_Float16)h;
        }
    }

    f16x8 a2[4];
#pragma unroll
    for (int ks = 0; ks < 4; ks++)
        a2[ks] = *(const f16x8*)&h16[w][lcol][ks * 32 + lgrp * 8];

    // ---- GEMM2: PHI = H @ W2 + b2, 3 chunks of 128 cols ----
    for (int ch = 0; ch < 3; ch++) {
#pragma unroll
        for (int c8 = 0; c8 < 8; c8++) {
            int ct = ch * 8 + c8;
            float bb = b2[ct * 16 + lcol];
            f32x4 acc = {bb, bb, bb, bb};
#pragma unroll
            for (int ks = 0; ks < 4; ks++) {
                f16x8 b = *(const f16x8*)(w2f + ((size_t)(ct * 4 + ks) * 64 + lane) * 8);
                acc = __builtin_amdgcn_mfma_f32_16x16x32_f16(a2[ks], b, acc, 0, 0, 0);
            }
#pragma unroll
            for (int r = 0; r < 4; r++)
                h16[w][lgrp * 4 + r][c8 * 16 + lcol] = (_Float16)acc[r];
        }
#pragma unroll
        for (int i = 0; i < 4; i++) {
            int flat = i * 64 + lane;
            int row = flat >> 4, cc = (flat & 15) * 8;
            int grow = base + r0 + row;
            if (grow < M) {
                f16x8 v = *(const f16x8*)&h16[w][row][cc];
                *(f16x8*)(PHI + (size_t)grow * OUTF + ch * 128 + cc) = v;
            }
        }
    }
}

// ---------------------------------------------------------------------------
// MFMA edge: out[e] = PHI[r_e] * (rbf(d_e) @ Wd + bd)
// 256 threads = 4 waves, 64 edges/block (16 per wave). Transposed tile:
// D[c][e] = sum_k Wd[k][c] * R[e][k]  (A = Wd fragments from wdf, B = R).
// Lane owns edge et+(lane&15); its 4 acc regs are 4 consecutive w_s cols
// c = ct*16 + (lane>>4)*4 + r  ->  f32x4 NT store + f16x4 PHI gather per ct.
// Each lane computes its edge's 20-step sin recurrence (4x dup, was 96x) and
// keeps only its lgrp's K-window (K padded to 32 with zeros). No LDS, no sync.
__global__ __launch_bounds__(256) void edge_mfma_kernel(
    const float* __restrict__ dist, const int* __restrict__ nbrs,
    const _Float16* __restrict__ PHI, const _Float16* __restrict__ wdf,
    const float* __restrict__ bd, float* __restrict__ out, int E)
{
    const int t = threadIdx.x;
    const int w = t >> 6, lane = t & 63;
    const int lcol = lane & 15, lgrp = lane >> 4;

    const int i64f = nbrs_is_i64(nbrs);
    const int e = blockIdx.x * 64 + w * 16 + lcol;
    const int ec = (e < E) ? e : (E - 1);
    const bool ok = (e < E);

    const float d = dist[ec];
    const int ridx = i64f ? nbrs[4 * (size_t)ec + 2] : nbrs[2 * (size_t)ec + 1];

    // R[e][k] = sin((k+1)*pi*d/5)/d via Chebyshev recurrence
    const float kx = (float)(M_PI / 5.0);
    float v[NRBF];
    {
        float s, c;
        __sincosf(d * kx, &s, &c);
        float rd = __frcp_rn(d);
        float t2 = 2.f * c;
        float sp = 0.f, sc = s;
        v[0] = s * rd;
#pragma unroll
        for (int n = 1; n < NRBF; n++) {
            float nx = t2 * sc - sp; sp = sc; sc = nx;
            v[n] = sc * rd;
        }
    }
    f16x8 bf;
    if (lgrp == 0)
        bf = (f16x8){(_Float16)v[0], (_Float16)v[1], (_Float16)v[2], (_Float16)v[3],
                     (_Float16)v[4], (_Float16)v[5], (_Float16)v[6], (_Float16)v[7]};
    else if (lgrp == 1)
        bf = (f16x8){(_Float16)v[8], (_Float16)v[9], (_Float16)v[10], (_Float16)v[11],
                     (_Float16)v[12], (_Float16)v[13], (_Float16)v[14], (_Float16)v[15]};
    else if (lgrp == 2)
        bf = (f16x8){(_Float16)v[16], (_Float16)v[17], (_Float16)v[18], (_Float16)v[19],
                     (_Float16)0.f, (_Float16)0.f, (_Float16)0.f, (_Float16)0.f};
    else
        bf = (f16x8){(_Float16)0.f, (_Float16)0.f, (_Float16)0.f, (_Float16)0.f,
                     (_Float16)0.f, (_Float16)0.f, (_Float16)0.f, (_Float16)0.f};

    const _Float16* phirow = PHI + (size_t)ridx * OUTF;
    float* orow = out + (size_t)ec * OUTF;

#pragma unroll 4
    for (int ct = 0; ct < 24; ct++) {
        const int c0 = ct * 16 + lgrp * 4;
        f16x8 af = *(const f16x8*)(wdf + ((size_t)(ct * 64 + lane)) * 8);
        f32x4 acc = *(const f32x4*)(bd + c0);
        acc = __builtin_amdgcn_mfma_f32_16x16x32_f16(af, bf, acc, 0, 0, 0);
        f16x4 p = *(const f16x4*)(phirow + c0);
        f32x4 o = {(float)p.x * acc[0], (float)p.y * acc[1],
                   (float)p.z * acc[2], (float)p.w * acc[3]};
        if (ok) __builtin_nontemporal_store(o, (f32x4*)(orow + c0));
    }
}

// ---------------------------------------------------------------------------
// Scalar fp32 phi (FALLBACK ONLY: per-edge, dst = d_out fp32)
template <bool GATHER>
__global__ __launch_bounds__(256) void phi_kernel(
    const float* __restrict__ s_j, const int* __restrict__ nbrs,
    const float* __restrict__ W1, const float* __restrict__ b1,
    const float* __restrict__ W2, const float* __restrict__ b2,
    float* __restrict__ dst, int M)
{
    __shared__ __align__(16) float st[FEAT][66];
    const int t = threadIdx.x;
    const int base = blockIdx.x * 64;

    int i64f = 0;
    if (GATHER) i64f = nbrs_is_i64(nbrs);

    for (int idx = t; idx < 64 * FEAT; idx += 256) {
        int n = idx >> 7, k = idx & 127;
        int row = base + n;
        float v = 0.f;
        if (row < M) {
            int src = GATHER ? (i64f ? nbrs[4 * (size_t)row + 2] : nbrs[2 * (size_t)row + 1])
                             : row;
            v = s_j[(size_t)src * FEAT + k];
        }
        st[k][n] = v;
    }
    __syncthreads();

    const int cg = t & 31, rg = t >> 5;
    const int c0 = cg * 4, r0 = rg * 8;

    float acc[8][4];
    {
        float4 b = *(const float4*)(b1 + c0);
#pragma unroll
        for (int i = 0; i < 8; i++) { acc[i][0] = b.x; acc[i][1] = b.y; acc[i][2] = b.z; acc[i][3] = b.w; }
#pragma unroll 4
        for (int k = 0; k < FEAT; k++) {
            float4 w = *(const float4*)(W1 + (size_t)k * FEAT + c0);
            float2 sa = *(const float2*)(&st[k][r0]);
            float2 sb = *(const float2*)(&st[k][r0 + 2]);
            float2 sc = *(const float2*)(&st[k][r0 + 4]);
            float2 sd = *(const float2*)(&st[k][r0 + 6]);
            float sv[8] = {sa.x, sa.y, sb.x, sb.y, sc.x, sc.y, sd.x, sd.y};
#pragma unroll
            for (int i = 0; i < 8; i++) {
                acc[i][0] += sv[i] * w.x; acc[i][1] += sv[i] * w.y;
                acc[i][2] += sv[i] * w.z; acc[i][3] += sv[i] * w.w;
            }
        }
    }
    __syncthreads();
#pragma unroll
    for (int i = 0; i < 8; i++)
#pragma unroll
        for (int j = 0; j < 4; j++) {
            float h = acc[i][j];
            h = h * __frcp_rn(1.f + __expf(-h));
            st[c0 + j][r0 + i] = h;
        }
    __syncthreads();

    for (int ch = 0; ch < 3; ch++) {
        const int oc = ch * 128 + c0;
        float4 b = *(const float4*)(b2 + oc);
#pragma unroll
        for (int i = 0; i < 8; i++) { acc[i][0] = b.x; acc[i][1] = b.y; acc[i][2] = b.z; acc[i][3] = b.w; }
#pragma unroll 4
        for (int k = 0; k < FEAT; k++) {
            float4 w = *(const float4*)(W2 + (size_t)k * OUTF + oc);
            float2 ha = *(const float2*)(&st[k][r0]);
            float2 hb = *(const float2*)(&st[k][r0 + 2]);
            float2 hc = *(const float2*)(&st[k][r0 + 4]);
            float2 hd = *(const float2*)(&st[k][r0 + 6]);
            float hv[8] = {ha.x, ha.y, hb.x, hb.y, hc.x, hc.y, hd.x, hd.y};
#pragma unroll
            for (int i = 0; i < 8; i++) {
                acc[i][0] += hv[i] * w.x; acc[i][1] += hv[i] * w.y;
                acc[i][2] += hv[i] * w.z; acc[i][3] += hv[i] * w.w;
            }
        }
#pragma unroll
        for (int i = 0; i < 8; i++) {
            int row = base + r0 + i;
            if (row < M) {
                float4 o = {acc[i][0], acc[i][1], acc[i][2], acc[i][3]};
                *(float4*)(dst + (size_t)row * OUTF + oc) = o;
            }
        }
    }
}

// ---------------------------------------------------------------------------
// Fallback edge: out[e] = phi_row * (rbf @ Wd + bd), fp32 phi in d_out (alias).
__global__ __launch_bounds__(384)
__attribute__((amdgpu_waves_per_eu(3, 3)))
void edge_kernel(
    const float* __restrict__ dist, const int* __restrict__ nbrs,
    const float* phi, const float* __restrict__ Wd,
    const float* __restrict__ bd, float* out, int E)
{
    __shared__ __align__(16) f32x4 wdl[NRBF][96];
    const int t = threadIdx.x;
    for (int idx = t; idx < NRBF * 96; idx += 384) {
        int n = idx / 96, qq = idx % 96;
        wdl[n][qq] = *(const f32x4*)(Wd + (size_t)n * OUTF + qq * 4);
    }
    __syncthreads();

    const int g = t / 96;
    const int q = t % 96;
    const int c0 = q * 4;
    f32x4 bdr = *(const f32x4*)(bd + c0);

    const float kx = (float)(M_PI / 5.0);
    const int stride = gridDim.x * 32;

    for (int e = (blockIdx.x * 4 + g) * 8; e < E; e += stride) {
        float d[8]; int r[8];
#pragma unroll
        for (int j = 0; j < 8; j++) {
            int ej = e + j; if (ej >= E) ej = E - 1;
            d[j] = dist[ej];
            r[j] = ej;
        }
        f32x4 p[8];
#pragma unroll
        for (int j = 0; j < 8; j++)
            p[j] = *(const f32x4*)(phi + (size_t)r[j] * OUTF + c0);

        float t2[8], sp[8], sc[8];
#pragma unroll
        for (int j = 0; j < 8; j++) {
            float s, c;
            __sincosf(d[j] * kx, &s, &c);
            sc[j] = s; t2[j] = 2.f * c; sp[j] = 0.f;
        }
        f32x4 a[8];
#pragma unroll
        for (int j = 0; j < 8; j++) a[j] = (f32x4){0.f, 0.f, 0.f, 0.f};
#pragma unroll
        for (int n = 0; n < NRBF; n++) {
            f32x4 wv = wdl[n][q];
#pragma unroll
            for (int j = 0; j < 8; j++) {
                a[j] += sc[j] * wv;
                float nx = t2[j] * sc[j] - sp[j]; sp[j] = sc[j]; sc[j] = nx;
            }
        }
#pragma unroll
        for (int j = 0; j < 8; j++) {
            if (e + j < E) {
                f32x4 o = p[j] * (a[j] * __frcp_rn(d[j]) + bdr);
                __builtin_nontemporal_store(o, (f32x4*)(out + (size_t)(e + j) * OUTF + c0));
            }
        }
    }
}

extern "C" void kernel_launch(void* const* d_in, const int* in_sizes, int n_in,
                              void* d_out, int out_size, void* d_ws, size_t ws_size,
                              hipStream_t stream)
{
    const float* s_j  = (const float*)d_in[0];
    const float* dist = (const float*)d_in[1];
    const int*   nbrs = (const int*)d_in[2];
    const float* W1   = (const float*)d_in[3];
    const float* b1   = (const float*)d_in[4];
    const float* W2   = (const float*)d_in[5];
    const float* b2   = (const float*)d_in[6];
    const float* Wd   = (const float*)d_in[7];
    const float* bd   = (const float*)d_in[8];
    float* out = (float*)d_out;

    const int N = in_sizes[0] / FEAT;
    const int E = in_sizes[1];
    if (E <= 0) return;

    const size_t phi_bytes = (size_t)N * OUTF * sizeof(_Float16);
    const size_t w1_off  = phi_bytes;
    const size_t w2_off  = w1_off + (size_t)8 * 4 * 64 * 8 * 2;
    const size_t wdf_off = w2_off + (size_t)24 * 4 * 64 * 8 * 2;
    const size_t need    = wdf_off + (size_t)24 * 64 * 8 * 2;

    if (ws_size >= need) {
        _Float16* PHI = (_Float16*)d_ws;
        _Float16* w1f = (_Float16*)((char*)d_ws + w1_off);
        _Float16* w2f = (_Float16*)((char*)d_ws + w2_off);
        _Float16* wdf = (_Float16*)((char*)d_ws + wdf_off);
        prep_w_kernel<<<38, 256, 0, stream>>>(W1, W2, Wd, w1f, w2f, wdf);
        phi_mfma_kernel<<<(N + 63) / 64, 256, 0, stream>>>(s_j, w1f, b1, w2f, b2, PHI, N);
        edge_mfma_kernel<<<(E + 63) / 64, 256, 0, stream>>>(dist, nbrs, PHI, wdf, bd, out, E);
    } else {
        // fallback: per-edge fp32 phi directly into d_out, then scale in place
        dim3 gA((E + 63) / 64);
        phi_kernel<true><<<gA, 256, 0, stream>>>(s_j, nbrs, W1, b1, W2, b2, out, E);
        int egrid = (E + 31) / 32;
        if (egrid > 2048) egrid = 2048;
        edge_kernel<<<egrid, 384, 0, stream>>>(dist, nbrs, out, Wd, bd, out, E);
    }
}

// Round 11
// 244.653 us; speedup vs baseline: 1.2595x; 1.2595x over previous
//
#include <hip/hip_runtime.h>
#include <math.h>

#define FEAT 128
#define OUTF 384
#define NRBF 20

typedef float f32x4 __attribute__((ext_vector_type(4)));
typedef _Float16 f16x4 __attribute__((ext_vector_type(4)));
typedef _Float16 f16x8 __attribute__((ext_vector_type(8)));

// Detect whether nbrs buffer is int64 (little-endian: odd int32 words are the
// high halves, all zero since indices < 50000) or genuine int32 pairs.
__device__ __forceinline__ int nbrs_is_i64(const int* nb) {
    int nz = 0;
#pragma unroll
    for (int i = 1; i < 64; i += 2) nz |= nb[i];
    return nz == 0;
}

// ---------------------------------------------------------------------------
// Convert W1 (128x128), W2 (128x384) to f16 B-fragment order and Wd (20x384)
// to f16 A-fragment order (K padded 20->32 with zeros) for mfma_f32_16x16x32:
// frag (ct, ks, lane) holds 8 f16: W[ks*32 + (lane>>4)*8 + j][ct*16 + (lane&15)]
__global__ __launch_bounds__(256) void prep_w_kernel(
    const float* __restrict__ W1, const float* __restrict__ W2,
    const float* __restrict__ Wd,
    _Float16* __restrict__ w1f, _Float16* __restrict__ w2f,
    _Float16* __restrict__ wdf)
{
    int idx = blockIdx.x * 256 + threadIdx.x;
    if (idx < 8 * 4 * 64) {                 // W1: 8 col-tiles x 4 k-steps
        int ct = idx >> 8, ks = (idx >> 6) & 3, lane = idx & 63;
        int lcol = lane & 15, lgrp = lane >> 4;
        _Float16* dst = w1f + (size_t)idx * 8;
        const float* src = W1 + (size_t)(ks * 32 + lgrp * 8) * FEAT + ct * 16 + lcol;
#pragma unroll
        for (int j = 0; j < 8; j++) dst[j] = (_Float16)src[(size_t)j * FEAT];
    } else if (idx < 8192) {                // W2: 24 col-tiles x 4 k-steps
        int i2 = idx - 2048;
        int ct = i2 >> 8, ks = (i2 >> 6) & 3, lane = i2 & 63;
        int lcol = lane & 15, lgrp = lane >> 4;
        _Float16* dst = w2f + (size_t)i2 * 8;
        const float* src = W2 + (size_t)(ks * 32 + lgrp * 8) * OUTF + ct * 16 + lcol;
#pragma unroll
        for (int j = 0; j < 8; j++) dst[j] = (_Float16)src[(size_t)j * OUTF];
    } else {                                // Wd: 24 col-tiles x 1 k-step (K=32, pad 20)
        int i3 = idx - 8192;
        if (i3 < 24 * 64) {
            int ct = i3 >> 6, lane = i3 & 63;
            int lcol = lane & 15, lgrp = lane >> 4;
            _Float16* dst = wdf + (size_t)i3 * 8;
#pragma unroll
            for (int j = 0; j < 8; j++) {
                int k = lgrp * 8 + j;
                dst[j] = (k < NRBF) ? (_Float16)Wd[(size_t)k * OUTF + ct * 16 + lcol]
                                    : (_Float16)0.f;
            }
        }
    }
}

// ---------------------------------------------------------------------------
// MFMA phi: PHI[row] = (silu(s_j[row] @ W1 + b1) @ W2 + b2) as fp16.
// 64 rows/block, 256 threads = 4 waves; wave w owns rows [w*16, w*16+16).
// mfma_f32_16x16x32_f16 layouts: A: row=lane&15, k=(lane>>4)*8+j;
// B: col=lane&15, same k; D: col=lane&15, row=(lane>>4)*4+reg.
__global__ __launch_bounds__(256) void phi_mfma_kernel(
    const float* __restrict__ s_j,
    const _Float16* __restrict__ w1f, const float* __restrict__ b1,
    const _Float16* __restrict__ w2f, const float* __restrict__ b2,
    _Float16* __restrict__ PHI, int M)
{
    __shared__ __align__(16) float s32[64][136];        // padded
    __shared__ __align__(16) _Float16 h16[4][16][144];  // wave-private H / PHI-chunk
    const int t = threadIdx.x;
    const int base = blockIdx.x * 64;

    for (int idx = t; idx < 64 * 32; idx += 256) {
        int row = idx >> 5, c4 = (idx & 31) * 4;
        float4 v = {0.f, 0.f, 0.f, 0.f};
        if (base + row < M) v = *(const float4*)(s_j + (size_t)(base + row) * FEAT + c4);
        *(float4*)&s32[row][c4] = v;
    }
    __syncthreads();

    const int w = t >> 6, lane = t & 63;
    const int lcol = lane & 15;
    const int lgrp = lane >> 4;
    const int r0 = w * 16;

    f16x8 a1[4];
#pragma unroll
    for (int ks = 0; ks < 4; ks++) {
        const float* p = &s32[r0 + lcol][ks * 32 + lgrp * 8];
        float4 u = *(const float4*)p;
        float4 v = *(const float4*)(p + 4);
        a1[ks] = (f16x8){(_Float16)u.x, (_Float16)u.y, (_Float16)u.z, (_Float16)u.w,
                         (_Float16)v.x, (_Float16)v.y, (_Float16)v.z, (_Float16)v.w};
    }

    // ---- GEMM1: H = silu(S @ W1 + b1) ----
#pragma unroll
    for (int ct = 0; ct < 8; ct++) {
        float bb = b1[ct * 16 + lcol];
        f32x4 acc = {bb, bb, bb, bb};
#pragma unroll
        for (int ks = 0; ks < 4; ks++) {
            f16x8 b = *(const f16x8*)(w1f + ((size_t)(ct * 4 + ks) * 64 + lane) * 8);
            acc = __builtin_amdgcn_mfma_f32_16x16x32_f16(a1[ks], b, acc, 0, 0, 0);
        }
#pragma unroll
        for (int r = 0; r < 4; r++) {
            float h = acc[r];
            h = h * __frcp_rn(1.f + __expf(-h));
            h16[w][lgrp * 4 + r][ct * 16 + lcol] = (_Float16)h;
        }
    }

    f16x8 a2[4];
#pragma unroll
    for (int ks = 0; ks < 4; ks++)
        a2[ks] = *(const f16x8*)&h16[w][lcol][ks * 32 + lgrp * 8];

    // ---- GEMM2: PHI = H @ W2 + b2, 3 chunks of 128 cols ----
    for (int ch = 0; ch < 3; ch++) {
#pragma unroll
        for (int c8 = 0; c8 < 8; c8++) {
            int ct = ch * 8 + c8;
            float bb = b2[ct * 16 + lcol];
            f32x4 acc = {bb, bb, bb, bb};
#pragma unroll
            for (int ks = 0; ks < 4; ks++) {
                f16x8 b = *(const f16x8*)(w2f + ((size_t)(ct * 4 + ks) * 64 + lane) * 8);
                acc = __builtin_amdgcn_mfma_f32_16x16x32_f16(a2[ks], b, acc, 0, 0, 0);
            }
#pragma unroll
            for (int r = 0; r < 4; r++)
                h16[w][lgrp * 4 + r][c8 * 16 + lcol] = (_Float16)acc[r];
        }
#pragma unroll
        for (int i = 0; i < 4; i++) {
            int flat = i * 64 + lane;
            int row = flat >> 4, cc = (flat & 15) * 8;
            int grow = base + r0 + row;
            if (grow < M) {
                f16x8 v = *(const f16x8*)&h16[w][row][cc];
                *(f16x8*)(PHI + (size_t)grow * OUTF + ch * 128 + cc) = v;
            }
        }
    }
}

// ---------------------------------------------------------------------------
// MFMA edge with LDS transpose: out[e] = PHI[r_e] * (rbf(d_e) @ Wd + bd)
// 256 threads = 4 waves, 64 edges/block.
// Phase 1: wave w owns edges w*16+lcol; each lane runs the 20-step sin
//   recurrence for ITS edge (4x dup, not 96x), 24 MFMAs compute the w_s tile
//   D[c][e] (A = Wd frags, B = R frags — r10-verified), results stored f16
//   into LDS ws[64][388] (~50 KB -> 3 blocks/CU = 12 waves/CU).
// Phase 2: flat loop (64 edges x 96 f32x4-chunks) / 256 threads: consecutive
//   threads cover consecutive cols of one edge row -> PHI gathers (8 B/lane,
//   768 B/row) and NT stores (16 B/lane, 1536 B/row) fully coalesced, exactly
//   r9's proven memory pattern; w_s comes from LDS.
__global__ __launch_bounds__(256) void edge_mfma_kernel(
    const float* __restrict__ dist, const int* __restrict__ nbrs,
    const _Float16* __restrict__ PHI, const _Float16* __restrict__ wdf,
    const float* __restrict__ bd, float* __restrict__ out, int E)
{
    __shared__ __align__(16) _Float16 ws[64][388];   // stride 776 B: 8B-aligned rows
    __shared__ int ridxs[64];

    const int t = threadIdx.x;
    const int w = t >> 6, lane = t & 63;
    const int lcol = lane & 15, lgrp = lane >> 4;

    const int i64f = nbrs_is_i64(nbrs);
    const int base = blockIdx.x * 64;
    const int el = w * 16 + lcol;
    const int e = base + el;
    const int ec = (e < E) ? e : (E - 1);

    const float d = dist[ec];
    const int ridx = i64f ? nbrs[4 * (size_t)ec + 2] : nbrs[2 * (size_t)ec + 1];
    if (lgrp == 0) ridxs[el] = ridx;

    // R[k] = sin((k+1)*pi*d/5)/d via Chebyshev recurrence
    const float kx = (float)(M_PI / 5.0);
    float v[NRBF];
    {
        float s, c;
        __sincosf(d * kx, &s, &c);
        float rd = __frcp_rn(d);
        float t2 = 2.f * c;
        float sp = 0.f, sc = s;
        v[0] = s * rd;
#pragma unroll
        for (int n = 1; n < NRBF; n++) {
            float nx = t2 * sc - sp; sp = sc; sc = nx;
            v[n] = sc * rd;
        }
    }
    f16x8 bf;
    if (lgrp == 0)
        bf = (f16x8){(_Float16)v[0], (_Float16)v[1], (_Float16)v[2], (_Float16)v[3],
                     (_Float16)v[4], (_Float16)v[5], (_Float16)v[6], (_Float16)v[7]};
    else if (lgrp == 1)
        bf = (f16x8){(_Float16)v[8], (_Float16)v[9], (_Float16)v[10], (_Float16)v[11],
                     (_Float16)v[12], (_Float16)v[13], (_Float16)v[14], (_Float16)v[15]};
    else if (lgrp == 2)
        bf = (f16x8){(_Float16)v[16], (_Float16)v[17], (_Float16)v[18], (_Float16)v[19],
                     (_Float16)0.f, (_Float16)0.f, (_Float16)0.f, (_Float16)0.f};
    else
        bf = (f16x8){(_Float16)0.f, (_Float16)0.f, (_Float16)0.f, (_Float16)0.f,
                     (_Float16)0.f, (_Float16)0.f, (_Float16)0.f, (_Float16)0.f};

    // Phase 1: w_s tile via MFMA -> LDS (f16)
#pragma unroll 4
    for (int ct = 0; ct < 24; ct++) {
        const int c0 = ct * 16 + lgrp * 4;
        f16x8 af = *(const f16x8*)(wdf + ((size_t)(ct * 64 + lane)) * 8);
        f32x4 acc = *(const f32x4*)(bd + c0);
        acc = __builtin_amdgcn_mfma_f32_16x16x32_f16(af, bf, acc, 0, 0, 0);
        f16x4 wsv = {(_Float16)acc[0], (_Float16)acc[1],
                     (_Float16)acc[2], (_Float16)acc[3]};
        *(f16x4*)&ws[el][c0] = wsv;
    }
    __syncthreads();

    // Phase 2: coalesced gather-multiply-store
#pragma unroll 4
    for (int i = 0; i < 24; i++) {
        int flat = i * 256 + t;          // 0..6143 = 64 edges x 96 chunks
        int el2 = flat / 96;
        int q4 = (flat - el2 * 96) * 4;
        int e2 = base + el2;
        if (e2 < E) {
            const _Float16* prow = PHI + (size_t)ridxs[el2] * OUTF;
            f16x4 p = *(const f16x4*)(prow + q4);
            f16x4 wv = *(const f16x4*)&ws[el2][q4];
            f32x4 o = {(float)p.x * (float)wv.x, (float)p.y * (float)wv.y,
                       (float)p.z * (float)wv.z, (float)p.w * (float)wv.w};
            __builtin_nontemporal_store(o, (f32x4*)(out + (size_t)e2 * OUTF + q4));
        }
    }
}

// ---------------------------------------------------------------------------
// Scalar fp32 phi (FALLBACK ONLY: per-edge, dst = d_out fp32)
template <bool GATHER>
__global__ __launch_bounds__(256) void phi_kernel(
    const float* __restrict__ s_j, const int* __restrict__ nbrs,
    const float* __restrict__ W1, const float* __restrict__ b1,
    const float* __restrict__ W2, const float* __restrict__ b2,
    float* __restrict__ dst, int M)
{
    __shared__ __align__(16) float st[FEAT][66];
    const int t = threadIdx.x;
    const int base = blockIdx.x * 64;

    int i64f = 0;
    if (GATHER) i64f = nbrs_is_i64(nbrs);

    for (int idx = t; idx < 64 * FEAT; idx += 256) {
        int n = idx >> 7, k = idx & 127;
        int row = base + n;
        float v = 0.f;
        if (row < M) {
            int src = GATHER ? (i64f ? nbrs[4 * (size_t)row + 2] : nbrs[2 * (size_t)row + 1])
                             : row;
            v = s_j[(size_t)src * FEAT + k];
        }
        st[k][n] = v;
    }
    __syncthreads();

    const int cg = t & 31, rg = t >> 5;
    const int c0 = cg * 4, r0 = rg * 8;

    float acc[8][4];
    {
        float4 b = *(const float4*)(b1 + c0);
#pragma unroll
        for (int i = 0; i < 8; i++) { acc[i][0] = b.x; acc[i][1] = b.y; acc[i][2] = b.z; acc[i][3] = b.w; }
#pragma unroll 4
        for (int k = 0; k < FEAT; k++) {
            float4 w = *(const float4*)(W1 + (size_t)k * FEAT + c0);
            float2 sa = *(const float2*)(&st[k][r0]);
            float2 sb = *(const float2*)(&st[k][r0 + 2]);
            float2 sc = *(const float2*)(&st[k][r0 + 4]);
            float2 sd = *(const float2*)(&st[k][r0 + 6]);
            float sv[8] = {sa.x, sa.y, sb.x, sb.y, sc.x, sc.y, sd.x, sd.y};
#pragma unroll
            for (int i = 0; i < 8; i++) {
                acc[i][0] += sv[i] * w.x; acc[i][1] += sv[i] * w.y;
                acc[i][2] += sv[i] * w.z; acc[i][3] += sv[i] * w.w;
            }
        }
    }
    __syncthreads();
#pragma unroll
    for (int i = 0; i < 8; i++)
#pragma unroll
        for (int j = 0; j < 4; j++) {
            float h = acc[i][j];
            h = h * __frcp_rn(1.f + __expf(-h));
            st[c0 + j][r0 + i] = h;
        }
    __syncthreads();

    for (int ch = 0; ch < 3; ch++) {
        const int oc = ch * 128 + c0;
        float4 b = *(const float4*)(b2 + oc);
#pragma unroll
        for (int i = 0; i < 8; i++) { acc[i][0] = b.x; acc[i][1] = b.y; acc[i][2] = b.z; acc[i][3] = b.w; }
#pragma unroll 4
        for (int k = 0; k < FEAT; k++) {
            float4 w = *(const float4*)(W2 + (size_t)k * OUTF + oc);
            float2 ha = *(const float2*)(&st[k][r0]);
            float2 hb = *(const float2*)(&st[k][r0 + 2]);
            float2 hc = *(const float2*)(&st[k][r0 + 4]);
            float2 hd = *(const float2*)(&st[k][r0 + 6]);
            float hv[8] = {ha.x, ha.y, hb.x, hb.y, hc.x, hc.y, hd.x, hd.y};
#pragma unroll
            for (int i = 0; i < 8; i++) {
                acc[i][0] += hv[i] * w.x; acc[i][1] += hv[i] * w.y;
                acc[i][2] += hv[i] * w.z; acc[i][3] += hv[i] * w.w;
            }
        }
#pragma unroll
        for (int i = 0; i < 8; i++) {
            int row = base + r0 + i;
            if (row < M) {
                float4 o = {acc[i][0], acc[i][1], acc[i][2], acc[i][3]};
                *(float4*)(dst + (size_t)row * OUTF + oc) = o;
            }
        }
    }
}

// ---------------------------------------------------------------------------
// Fallback edge: out[e] = phi_row * (rbf @ Wd + bd), fp32 phi in d_out (alias).
__global__ __launch_bounds__(384)
__attribute__((amdgpu_waves_per_eu(3, 3)))
void edge_kernel(
    const float* __restrict__ dist, const int* __restrict__ nbrs,
    const float* phi, const float* __restrict__ Wd,
    const float* __restrict__ bd, float* out, int E)
{
    __shared__ __align__(16) f32x4 wdl[NRBF][96];
    const int t = threadIdx.x;
    for (int idx = t; idx < NRBF * 96; idx += 384) {
        int n = idx / 96, qq = idx % 96;
        wdl[n][qq] = *(const f32x4*)(Wd + (size_t)n * OUTF + qq * 4);
    }
    __syncthreads();

    const int g = t / 96;
    const int q = t % 96;
    const int c0 = q * 4;
    f32x4 bdr = *(const f32x4*)(bd + c0);

    const float kx = (float)(M_PI / 5.0);
    const int stride = gridDim.x * 32;

    for (int e = (blockIdx.x * 4 + g) * 8; e < E; e += stride) {
        float d[8]; int r[8];
#pragma unroll
        for (int j = 0; j < 8; j++) {
            int ej = e + j; if (ej >= E) ej = E - 1;
            d[j] = dist[ej];
            r[j] = ej;
        }
        f32x4 p[8];
#pragma unroll
        for (int j = 0; j < 8; j++)
            p[j] = *(const f32x4*)(phi + (size_t)r[j] * OUTF + c0);

        float t2[8], sp[8], sc[8];
#pragma unroll
        for (int j = 0; j < 8; j++) {
            float s, c;
            __sincosf(d[j] * kx, &s, &c);
            sc[j] = s; t2[j] = 2.f * c; sp[j] = 0.f;
        }
        f32x4 a[8];
#pragma unroll
        for (int j = 0; j < 8; j++) a[j] = (f32x4){0.f, 0.f, 0.f, 0.f};
#pragma unroll
        for (int n = 0; n < NRBF; n++) {
            f32x4 wv = wdl[n][q];
#pragma unroll
            for (int j = 0; j < 8; j++) {
                a[j] += sc[j] * wv;
                float nx = t2[j] * sc[j] - sp[j]; sp[j] = sc[j]; sc[j] = nx;
            }
        }
#pragma unroll
        for (int j = 0; j < 8; j++) {
            if (e + j < E) {
                f32x4 o = p[j] * (a[j] * __frcp_rn(d[j]) + bdr);
                __builtin_nontemporal_store(o, (f32x4*)(out + (size_t)(e + j) * OUTF + c0));
            }
        }
    }
}

extern "C" void kernel_launch(void* const* d_in, const int* in_sizes, int n_in,
                              void* d_out, int out_size, void* d_ws, size_t ws_size,
                              hipStream_t stream)
{
    const float* s_j  = (const float*)d_in[0];
    const float* dist = (const float*)d_in[1];
    const int*   nbrs = (const int*)d_in[2];
    const float* W1   = (const float*)d_in[3];
    const float* b1   = (const float*)d_in[4];
    const float* W2   = (const float*)d_in[5];
    const float* b2   = (const float*)d_in[6];
    const float* Wd   = (const float*)d_in[7];
    const float* bd   = (const float*)d_in[8];
    float* out = (float*)d_out;

    const int N = in_sizes[0] / FEAT;
    const int E = in_sizes[1];
    if (E <= 0) return;

    const size_t phi_bytes = (size_t)N * OUTF * sizeof(_Float16);
    const size_t w1_off  = phi_bytes;
    const size_t w2_off  = w1_off + (size_t)8 * 4 * 64 * 8 * 2;
    const size_t wdf_off = w2_off + (size_t)24 * 4 * 64 * 8 * 2;
    const size_t need    = wdf_off + (size_t)24 * 64 * 8 * 2;

    if (ws_size >= need) {
        _Float16* PHI = (_Float16*)d_ws;
        _Float16* w1f = (_Float16*)((char*)d_ws + w1_off);
        _Float16* w2f = (_Float16*)((char*)d_ws + w2_off);
        _Float16* wdf = (_Float16*)((char*)d_ws + wdf_off);
        prep_w_kernel<<<38, 256, 0, stream>>>(W1, W2, Wd, w1f, w2f, wdf);
        phi_mfma_kernel<<<(N + 63) / 64, 256, 0, stream>>>(s_j, w1f, b1, w2f, b2, PHI, N);
        edge_mfma_kernel<<<(E + 63) / 64, 256, 0, stream>>>(dist, nbrs, PHI, wdf, bd, out, E);
    } else {
        // fallback: per-edge fp32 phi directly into d_out, then scale in place
        dim3 gA((E + 63) / 64);
        phi_kernel<true><<<gA, 256, 0, stream>>>(s_j, nbrs, W1, b1, W2, b2, out, E);
        int egrid = (E + 31) / 32;
        if (egrid > 2048) egrid = 2048;
        edge_kernel<<<egrid, 384, 0, stream>>>(dist, nbrs, out, Wd, bd, out, E);
    }
}

// Round 12
// 241.837 us; speedup vs baseline: 1.2742x; 1.0116x over previous
//
#include <hip/hip_runtime.h>
#include <math.h>

#define FEAT 128
#define OUTF 384
#define NRBF 20

typedef float f32x4 __attribute__((ext_vector_type(4)));
typedef _Float16 f16x4 __attribute__((ext_vector_type(4)));
typedef _Float16 f16x8 __attribute__((ext_vector_type(8)));

// Detect whether nbrs buffer is int64 (little-endian: odd int32 words are the
// high halves, all zero since indices < 50000) or genuine int32 pairs.
__device__ __forceinline__ int nbrs_is_i64(const int* nb) {
    int nz = 0;
#pragma unroll
    for (int i = 1; i < 64; i += 2) nz |= nb[i];
    return nz == 0;
}

// ---------------------------------------------------------------------------
// Convert W1 (128x128), W2 (128x384) to f16 B-fragment order and Wd (20x384)
// to f16 A-fragment order (K padded 20->32 with zeros) for mfma_f32_16x16x32:
// frag (ct, ks, lane) holds 8 f16: W[ks*32 + (lane>>4)*8 + j][ct*16 + (lane&15)]
// Also writes the nbrs-int64 flag once (read back by edge kernel as a
// uniform scalar load instead of 32 strided loads per thread).
__global__ __launch_bounds__(256) void prep_w_kernel(
    const float* __restrict__ W1, const float* __restrict__ W2,
    const float* __restrict__ Wd, const int* __restrict__ nbrs,
    _Float16* __restrict__ w1f, _Float16* __restrict__ w2f,
    _Float16* __restrict__ wdf, int* __restrict__ flag)
{
    int idx = blockIdx.x * 256 + threadIdx.x;
    if (idx == 0) flag[0] = nbrs_is_i64(nbrs);
    if (idx < 8 * 4 * 64) {                 // W1: 8 col-tiles x 4 k-steps
        int ct = idx >> 8, ks = (idx >> 6) & 3, lane = idx & 63;
        int lcol = lane & 15, lgrp = lane >> 4;
        _Float16* dst = w1f + (size_t)idx * 8;
        const float* src = W1 + (size_t)(ks * 32 + lgrp * 8) * FEAT + ct * 16 + lcol;
#pragma unroll
        for (int j = 0; j < 8; j++) dst[j] = (_Float16)src[(size_t)j * FEAT];
    } else if (idx < 8192) {                // W2: 24 col-tiles x 4 k-steps
        int i2 = idx - 2048;
        int ct = i2 >> 8, ks = (i2 >> 6) & 3, lane = i2 & 63;
        int lcol = lane & 15, lgrp = lane >> 4;
        _Float16* dst = w2f + (size_t)i2 * 8;
        const float* src = W2 + (size_t)(ks * 32 + lgrp * 8) * OUTF + ct * 16 + lcol;
#pragma unroll
        for (int j = 0; j < 8; j++) dst[j] = (_Float16)src[(size_t)j * OUTF];
    } else {                                // Wd: 24 col-tiles x 1 k-step (K=32, pad 20)
        int i3 = idx - 8192;
        if (i3 < 24 * 64) {
            int ct = i3 >> 6, lane = i3 & 63;
            int lcol = lane & 15, lgrp = lane >> 4;
            _Float16* dst = wdf + (size_t)i3 * 8;
#pragma unroll
            for (int j = 0; j < 8; j++) {
                int k = lgrp * 8 + j;
                dst[j] = (k < NRBF) ? (_Float16)Wd[(size_t)k * OUTF + ct * 16 + lcol]
                                    : (_Float16)0.f;
            }
        }
    }
}

// ---------------------------------------------------------------------------
// MFMA phi: PHI[row] = (silu(s_j[row] @ W1 + b1) @ W2 + b2) as fp16.
// 64 rows/block, 256 threads = 4 waves; wave w owns rows [w*16, w*16+16).
// mfma_f32_16x16x32_f16 layouts: A: row=lane&15, k=(lane>>4)*8+j;
// B: col=lane&15, same k; D: col=lane&15, row=(lane>>4)*4+reg.
__global__ __launch_bounds__(256) void phi_mfma_kernel(
    const float* __restrict__ s_j,
    const _Float16* __restrict__ w1f, const float* __restrict__ b1,
    const _Float16* __restrict__ w2f, const float* __restrict__ b2,
    _Float16* __restrict__ PHI, int M)
{
    __shared__ __align__(16) float s32[64][136];        // padded
    __shared__ __align__(16) _Float16 h16[4][16][144];  // wave-private H / PHI-chunk
    const int t = threadIdx.x;
    const int base = blockIdx.x * 64;

    for (int idx = t; idx < 64 * 32; idx += 256) {
        int row = idx >> 5, c4 = (idx & 31) * 4;
        float4 v = {0.f, 0.f, 0.f, 0.f};
        if (base + row < M) v = *(const float4*)(s_j + (size_t)(base + row) * FEAT + c4);
        *(float4*)&s32[row][c4] = v;
    }
    __syncthreads();

    const int w = t >> 6, lane = t & 63;
    const int lcol = lane & 15;
    const int lgrp = lane >> 4;
    const int r0 = w * 16;

    f16x8 a1[4];
#pragma unroll
    for (int ks = 0; ks < 4; ks++) {
        const float* p = &s32[r0 + lcol][ks * 32 + lgrp * 8];
        float4 u = *(const float4*)p;
        float4 v = *(const float4*)(p + 4);
        a1[ks] = (f16x8){(_Float16)u.x, (_Float16)u.y, (_Float16)u.z, (_Float16)u.w,
                         (_Float16)v.x, (_Float16)v.y, (_Float16)v.z, (_Float16)v.w};
    }

    // ---- GEMM1: H = silu(S @ W1 + b1) ----
#pragma unroll
    for (int ct = 0; ct < 8; ct++) {
        float bb = b1[ct * 16 + lcol];
        f32x4 acc = {bb, bb, bb, bb};
#pragma unroll
        for (int ks = 0; ks < 4; ks++) {
            f16x8 b = *(const f16x8*)(w1f + ((size_t)(ct * 4 + ks) * 64 + lane) * 8);
            acc = __builtin_amdgcn_mfma_f32_16x16x32_f16(a1[ks], b, acc, 0, 0, 0);
        }
#pragma unroll
        for (int r = 0; r < 4; r++) {
            float h = acc[r];
            h = h * __frcp_rn(1.f + __expf(-h));
            h16[w][lgrp * 4 + r][ct * 16 + lcol] = (_Float16)h;
        }
    }

    f16x8 a2[4];
#pragma unroll
    for (int ks = 0; ks < 4; ks++)
        a2[ks] = *(const f16x8*)&h16[w][lcol][ks * 32 + lgrp * 8];

    // ---- GEMM2: PHI = H @ W2 + b2, 3 chunks of 128 cols ----
    for (int ch = 0; ch < 3; ch++) {
#pragma unroll
        for (int c8 = 0; c8 < 8; c8++) {
            int ct = ch * 8 + c8;
            float bb = b2[ct * 16 + lcol];
            f32x4 acc = {bb, bb, bb, bb};
#pragma unroll
            for (int ks = 0; ks < 4; ks++) {
                f16x8 b = *(const f16x8*)(w2f + ((size_t)(ct * 4 + ks) * 64 + lane) * 8);
                acc = __builtin_amdgcn_mfma_f32_16x16x32_f16(a2[ks], b, acc, 0, 0, 0);
            }
#pragma unroll
            for (int r = 0; r < 4; r++)
                h16[w][lgrp * 4 + r][c8 * 16 + lcol] = (_Float16)acc[r];
        }
#pragma unroll
        for (int i = 0; i < 4; i++) {
            int flat = i * 64 + lane;
            int row = flat >> 4, cc = (flat & 15) * 8;
            int grow = base + r0 + row;
            if (grow < M) {
                f16x8 v = *(const f16x8*)&h16[w][row][cc];
                *(f16x8*)(PHI + (size_t)grow * OUTF + ch * 128 + cc) = v;
            }
        }
    }
}

// ---------------------------------------------------------------------------
// MFMA edge with LDS transpose: out[e] = PHI[r_e] * (rbf(d_e) @ Wd + bd)
// 128 threads = 2 waves, 32 edges/block (25 KB LDS -> 6 blocks/CU: finer
// phase interleave across blocks than r11's 64-edge/50 KB/3-block version,
// and the phase barrier spans only 2 waves).
// Phase 1: wave w owns edges w*16+lcol; each lane runs the 20-step sin
//   recurrence for ITS edge, 24 MFMAs compute the w_s tile D[c][e]
//   (A = Wd frags, B = R frags), stored f16 into LDS ws[32][388].
// Phase 2: flat loop (32 edges x 96 f32x4-chunks) / 128 threads: consecutive
//   threads cover consecutive cols of one edge row -> PHI gathers (8 B/lane)
//   and NT stores (16 B/lane) fully coalesced; w_s comes from LDS.
__global__ __launch_bounds__(128) void edge_mfma_kernel(
    const float* __restrict__ dist, const int* __restrict__ nbrs,
    const _Float16* __restrict__ PHI, const _Float16* __restrict__ wdf,
    const float* __restrict__ bd, float* __restrict__ out,
    const int* __restrict__ flag, int E)
{
    __shared__ __align__(16) _Float16 ws[32][388];   // stride 776 B (bank-spread)
    __shared__ int ridxs[32];

    const int t = threadIdx.x;
    const int w = t >> 6, lane = t & 63;
    const int lcol = lane & 15, lgrp = lane >> 4;

    const int i64f = flag[0];                        // uniform scalar load
    const int base = blockIdx.x * 32;
    const int el = w * 16 + lcol;
    const int e = base + el;
    const int ec = (e < E) ? e : (E - 1);

    const float d = dist[ec];
    const int ridx = i64f ? nbrs[4 * (size_t)ec + 2] : nbrs[2 * (size_t)ec + 1];
    if (lgrp == 0) ridxs[el] = ridx;

    // R[k] = sin((k+1)*pi*d/5)/d via Chebyshev recurrence
    const float kx = (float)(M_PI / 5.0);
    float v[NRBF];
    {
        float s, c;
        __sincosf(d * kx, &s, &c);
        float rd = __frcp_rn(d);
        float t2 = 2.f * c;
        float sp = 0.f, sc = s;
        v[0] = s * rd;
#pragma unroll
        for (int n = 1; n < NRBF; n++) {
            float nx = t2 * sc - sp; sp = sc; sc = nx;
            v[n] = sc * rd;
        }
    }
    f16x8 bf;
    if (lgrp == 0)
        bf = (f16x8){(_Float16)v[0], (_Float16)v[1], (_Float16)v[2], (_Float16)v[3],
                     (_Float16)v[4], (_Float16)v[5], (_Float16)v[6], (_Float16)v[7]};
    else if (lgrp == 1)
        bf = (f16x8){(_Float16)v[8], (_Float16)v[9], (_Float16)v[10], (_Float16)v[11],
                     (_Float16)v[12], (_Float16)v[13], (_Float16)v[14], (_Float16)v[15]};
    else if (lgrp == 2)
        bf = (f16x8){(_Float16)v[16], (_Float16)v[17], (_Float16)v[18], (_Float16)v[19],
                     (_Float16)0.f, (_Float16)0.f, (_Float16)0.f, (_Float16)0.f};
    else
        bf = (f16x8){(_Float16)0.f, (_Float16)0.f, (_Float16)0.f, (_Float16)0.f,
                     (_Float16)0.f, (_Float16)0.f, (_Float16)0.f, (_Float16)0.f};

    // Phase 1: w_s tile via MFMA -> LDS (f16)
#pragma unroll 4
    for (int ct = 0; ct < 24; ct++) {
        const int c0 = ct * 16 + lgrp * 4;
        f16x8 af = *(const f16x8*)(wdf + ((size_t)(ct * 64 + lane)) * 8);
        f32x4 acc = *(const f32x4*)(bd + c0);
        acc = __builtin_amdgcn_mfma_f32_16x16x32_f16(af, bf, acc, 0, 0, 0);
        f16x4 wsv = {(_Float16)acc[0], (_Float16)acc[1],
                     (_Float16)acc[2], (_Float16)acc[3]};
        *(f16x4*)&ws[el][c0] = wsv;
    }
    __syncthreads();

    // Phase 2: coalesced gather-multiply-store (32 edges x 96 chunks / 128 thr)
#pragma unroll 4
    for (int i = 0; i < 24; i++) {
        int flat = i * 128 + t;          // 0..3071
        int el2 = flat / 96;
        int q4 = (flat - el2 * 96) * 4;
        int e2 = base + el2;
        if (e2 < E) {
            const _Float16* prow = PHI + (size_t)ridxs[el2] * OUTF;
            f16x4 p = *(const f16x4*)(prow + q4);
            f16x4 wv = *(const f16x4*)&ws[el2][q4];
            f32x4 o = {(float)p.x * (float)wv.x, (float)p.y * (float)wv.y,
                       (float)p.z * (float)wv.z, (float)p.w * (float)wv.w};
            __builtin_nontemporal_store(o, (f32x4*)(out + (size_t)e2 * OUTF + q4));
        }
    }
}

// ---------------------------------------------------------------------------
// Scalar fp32 phi (FALLBACK ONLY: per-edge, dst = d_out fp32)
template <bool GATHER>
__global__ __launch_bounds__(256) void phi_kernel(
    const float* __restrict__ s_j, const int* __restrict__ nbrs,
    const float* __restrict__ W1, const float* __restrict__ b1,
    const float* __restrict__ W2, const float* __restrict__ b2,
    float* __restrict__ dst, int M)
{
    __shared__ __align__(16) float st[FEAT][66];
    const int t = threadIdx.x;
    const int base = blockIdx.x * 64;

    int i64f = 0;
    if (GATHER) i64f = nbrs_is_i64(nbrs);

    for (int idx = t; idx < 64 * FEAT; idx += 256) {
        int n = idx >> 7, k = idx & 127;
        int row = base + n;
        float v = 0.f;
        if (row < M) {
            int src = GATHER ? (i64f ? nbrs[4 * (size_t)row + 2] : nbrs[2 * (size_t)row + 1])
                             : row;
            v = s_j[(size_t)src * FEAT + k];
        }
        st[k][n] = v;
    }
    __syncthreads();

    const int cg = t & 31, rg = t >> 5;
    const int c0 = cg * 4, r0 = rg * 8;

    float acc[8][4];
    {
        float4 b = *(const float4*)(b1 + c0);
#pragma unroll
        for (int i = 0; i < 8; i++) { acc[i][0] = b.x; acc[i][1] = b.y; acc[i][2] = b.z; acc[i][3] = b.w; }
#pragma unroll 4
        for (int k = 0; k < FEAT; k++) {
            float4 w = *(const float4*)(W1 + (size_t)k * FEAT + c0);
            float2 sa = *(const float2*)(&st[k][r0]);
            float2 sb = *(const float2*)(&st[k][r0 + 2]);
            float2 sc = *(const float2*)(&st[k][r0 + 4]);
            float2 sd = *(const float2*)(&st[k][r0 + 6]);
            float sv[8] = {sa.x, sa.y, sb.x, sb.y, sc.x, sc.y, sd.x, sd.y};
#pragma unroll
            for (int i = 0; i < 8; i++) {
                acc[i][0] += sv[i] * w.x; acc[i][1] += sv[i] * w.y;
                acc[i][2] += sv[i] * w.z; acc[i][3] += sv[i] * w.w;
            }
        }
    }
    __syncthreads();
#pragma unroll
    for (int i = 0; i < 8; i++)
#pragma unroll
        for (int j = 0; j < 4; j++) {
            float h = acc[i][j];
            h = h * __frcp_rn(1.f + __expf(-h));
            st[c0 + j][r0 + i] = h;
        }
    __syncthreads();

    for (int ch = 0; ch < 3; ch++) {
        const int oc = ch * 128 + c0;
        float4 b = *(const float4*)(b2 + oc);
#pragma unroll
        for (int i = 0; i < 8; i++) { acc[i][0] = b.x; acc[i][1] = b.y; acc[i][2] = b.z; acc[i][3] = b.w; }
#pragma unroll 4
        for (int k = 0; k < FEAT; k++) {
            float4 w = *(const float4*)(W2 + (size_t)k * OUTF + oc);
            float2 ha = *(const float2*)(&st[k][r0]);
            float2 hb = *(const float2*)(&st[k][r0 + 2]);
            float2 hc = *(const float2*)(&st[k][r0 + 4]);
            float2 hd = *(const float2*)(&st[k][r0 + 6]);
            float hv[8] = {ha.x, ha.y, hb.x, hb.y, hc.x, hc.y, hd.x, hd.y};
#pragma unroll
            for (int i = 0; i < 8; i++) {
                acc[i][0] += hv[i] * w.x; acc[i][1] += hv[i] * w.y;
                acc[i][2] += hv[i] * w.z; acc[i][3] += hv[i] * w.w;
            }
        }
#pragma unroll
        for (int i = 0; i < 8; i++) {
            int row = base + r0 + i;
            if (row < M) {
                float4 o = {acc[i][0], acc[i][1], acc[i][2], acc[i][3]};
                *(float4*)(dst + (size_t)row * OUTF + oc) = o;
            }
        }
    }
}

// ---------------------------------------------------------------------------
// Fallback edge: out[e] = phi_row * (rbf @ Wd + bd), fp32 phi in d_out (alias).
__global__ __launch_bounds__(384)
__attribute__((amdgpu_waves_per_eu(3, 3)))
void edge_kernel(
    const float* __restrict__ dist, const int* __restrict__ nbrs,
    const float* phi, const float* __restrict__ Wd,
    const float* __restrict__ bd, float* out, int E)
{
    __shared__ __align__(16) f32x4 wdl[NRBF][96];
    const int t = threadIdx.x;
    for (int idx = t; idx < NRBF * 96; idx += 384) {
        int n = idx / 96, qq = idx % 96;
        wdl[n][qq] = *(const f32x4*)(Wd + (size_t)n * OUTF + qq * 4);
    }
    __syncthreads();

    const int g = t / 96;
    const int q = t % 96;
    const int c0 = q * 4;
    f32x4 bdr = *(const f32x4*)(bd + c0);

    const float kx = (float)(M_PI / 5.0);
    const int stride = gridDim.x * 32;

    for (int e = (blockIdx.x * 4 + g) * 8; e < E; e += stride) {
        float d[8]; int r[8];
#pragma unroll
        for (int j = 0; j < 8; j++) {
            int ej = e + j; if (ej >= E) ej = E - 1;
            d[j] = dist[ej];
            r[j] = ej;
        }
        f32x4 p[8];
#pragma unroll
        for (int j = 0; j < 8; j++)
            p[j] = *(const f32x4*)(phi + (size_t)r[j] * OUTF + c0);

        float t2[8], sp[8], sc[8];
#pragma unroll
        for (int j = 0; j < 8; j++) {
            float s, c;
            __sincosf(d[j] * kx, &s, &c);
            sc[j] = s; t2[j] = 2.f * c; sp[j] = 0.f;
        }
        f32x4 a[8];
#pragma unroll
        for (int j = 0; j < 8; j++) a[j] = (f32x4){0.f, 0.f, 0.f, 0.f};
#pragma unroll
        for (int n = 0; n < NRBF; n++) {
            f32x4 wv = wdl[n][q];
#pragma unroll
            for (int j = 0; j < 8; j++) {
                a[j] += sc[j] * wv;
                float nx = t2[j] * sc[j] - sp[j]; sp[j] = sc[j]; sc[j] = nx;
            }
        }
#pragma unroll
        for (int j = 0; j < 8; j++) {
            if (e + j < E) {
                f32x4 o = p[j] * (a[j] * __frcp_rn(d[j]) + bdr);
                __builtin_nontemporal_store(o, (f32x4*)(out + (size_t)(e + j) * OUTF + c0));
            }
        }
    }
}

extern "C" void kernel_launch(void* const* d_in, const int* in_sizes, int n_in,
                              void* d_out, int out_size, void* d_ws, size_t ws_size,
                              hipStream_t stream)
{
    const float* s_j  = (const float*)d_in[0];
    const float* dist = (const float*)d_in[1];
    const int*   nbrs = (const int*)d_in[2];
    const float* W1   = (const float*)d_in[3];
    const float* b1   = (const float*)d_in[4];
    const float* W2   = (const float*)d_in[5];
    const float* b2   = (const float*)d_in[6];
    const float* Wd   = (const float*)d_in[7];
    const float* bd   = (const float*)d_in[8];
    float* out = (float*)d_out;

    const int N = in_sizes[0] / FEAT;
    const int E = in_sizes[1];
    if (E <= 0) return;

    const size_t phi_bytes = (size_t)N * OUTF * sizeof(_Float16);
    const size_t w1_off   = phi_bytes;
    const size_t w2_off   = w1_off + (size_t)8 * 4 * 64 * 8 * 2;
    const size_t wdf_off  = w2_off + (size_t)24 * 4 * 64 * 8 * 2;
    const size_t flag_off = wdf_off + (size_t)24 * 64 * 8 * 2;
    const size_t need     = flag_off + 16;

    if (ws_size >= need) {
        _Float16* PHI = (_Float16*)d_ws;
        _Float16* w1f = (_Float16*)((char*)d_ws + w1_off);
        _Float16* w2f = (_Float16*)((char*)d_ws + w2_off);
        _Float16* wdf = (_Float16*)((char*)d_ws + wdf_off);
        int* flag     = (int*)((char*)d_ws + flag_off);
        prep_w_kernel<<<38, 256, 0, stream>>>(W1, W2, Wd, nbrs, w1f, w2f, wdf, flag);
        phi_mfma_kernel<<<(N + 63) / 64, 256, 0, stream>>>(s_j, w1f, b1, w2f, b2, PHI, N);
        edge_mfma_kernel<<<(E + 31) / 32, 128, 0, stream>>>(dist, nbrs, PHI, wdf, bd, out, flag, E);
    } else {
        // fallback: per-edge fp32 phi directly into d_out, then scale in place
        dim3 gA((E + 63) / 64);
        phi_kernel<true><<<gA, 256, 0, stream>>>(s_j, nbrs, W1, b1, W2, b2, out, E);
        int egrid = (E + 31) / 32;
        if (egrid > 2048) egrid = 2048;
        edge_kernel<<<egrid, 384, 0, stream>>>(dist, nbrs, out, Wd, bd, out, E);
    }
}